// Round 5
// baseline (95.267 us; speedup 1.0000x reference)
//
#include <hip/hip_runtime.h>
#include <hip/hip_bf16.h>

// RoI crop: out[n,b,i,j,c] = features[b, x1(n)+i, y1(n)+j, c]
// features: [B=8, 64, 64, C=256] f32 ; boxes: [N=1000, 4] i32 (x1,y1,x2,y2)
// out: [N, B, 7, 7, C] f32  (401 MB streaming write)
//
// R4: same as R3 but PLAIN stores (drop nontemporal). Store source-reg
// reuse needs s_waitcnt vmcnt (WAR hazard); nt stores ack slowly (bypass
// path), so each wave stalled on store drain before reloading v[].
// Plain stores ack at L2; write-back streams full lines to HBM at the
// ~6.8 TB/s the fill kernel demonstrates.
//  - XCD-pinned batch slices: b = blockIdx&7 -> each XCD L2 holds exactly
//    its 4 MB feature slice; reads are L2 hits.
//  - 2000 blocks x 4 waves; wave = one (n,b): 49 rows x 1 KB contiguous.

#define ANCHOR 7
#define FS     64
#define NBOX   1000
#define BB     8
#define CC     256
#define C4     (CC / 4)                 // 64 f32x4 per row
#define ROWS   (BB * ANCHOR * ANCHOR)   // 392 rows per box

typedef float f32x4 __attribute__((ext_vector_type(4)));

__global__ __launch_bounds__(256) void roi_crop_kernel(
    const f32x4* __restrict__ fin,      // features as f32x4
    const int*   __restrict__ boxes,    // [N,4]
    f32x4*       __restrict__ fout)     // out as f32x4
{
    const int lane = threadIdx.x & 63;
    const int wave = threadIdx.x >> 6;          // 0..3
    const int x    = blockIdx.x;                // 0..1999
    const int b    = x & 7;                     // batch slice == XCD id
    const int n    = (x >> 3) * 4 + wave;       // box index, 0..999

    int x1 = boxes[n * 4 + 0];
    int y1 = boxes[n * 4 + 1];
    x1 = min(max(x1, 0), FS - ANCHOR);
    y1 = min(max(y1, 0), FS - ANCHOR);

    const f32x4* __restrict__ src = fin + ((b * FS + x1) * FS + y1) * C4 + lane;
    f32x4* __restrict__ dst = fout + n * (ROWS * C4) + b * (ANCHOR * ANCHOR * C4) + lane;

    #pragma unroll
    for (int i = 0; i < ANCHOR; ++i) {
        f32x4 v[ANCHOR];
        #pragma unroll
        for (int j = 0; j < ANCHOR; ++j)
            v[j] = src[(i * FS + j) * C4];      // 7 loads issued back-to-back
        #pragma unroll
        for (int j = 0; j < ANCHOR; ++j)
            dst[(i * ANCHOR + j) * C4] = v[j];  // plain stores: fast L2 ack
    }
}

extern "C" void kernel_launch(void* const* d_in, const int* in_sizes, int n_in,
                              void* d_out, int out_size, void* d_ws, size_t ws_size,
                              hipStream_t stream) {
    const f32x4* fin  = (const f32x4*)d_in[0];
    const int*  boxes = (const int*)d_in[1];
    f32x4*      fout  = (f32x4*)d_out;

    roi_crop_kernel<<<NBOX * BB / 4, 256, 0, stream>>>(fin, boxes, fout);
}

// Round 6
// 80.865 us; speedup vs baseline: 1.1781x; 1.1781x over previous
//
#include <hip/hip_runtime.h>
#include <hip/hip_bf16.h>

// RoI crop: out[n,b,i,j,c] = features[b, x1(n)+i, y1(n)+j, c]
// features: [B=8, 64, 64, C=256] f32 ; boxes: [N=1000, 4] i32 (x1,y1,x2,y2)
// out: [N, B, 7, 7, C] f32  (401 MB streaming write)
//
// R5: R3 (nt stores + XCD-pinned batch slices) + 1-row double-buffer
// software pipeline. R4 proved plain stores thrash L2 (-16%); nt stays.
// R3's v[] reuse forced a vmcnt wait on nt-store COMPLETION (WAR) every
// row; double-buffering moves the reuse 14 VMEM ops later so the wait is
// pre-satisfied. Outer loop fully unrolled -> compile-time buffer indices.
//  - XCD-pinned: b = blockIdx&7; each XCD L2 holds its 4 MB feature slice.
//  - 2000 blocks x 4 waves; wave = one (n,b): 49 rows x 1 KB contiguous.

#define ANCHOR 7
#define FS     64
#define NBOX   1000
#define BB     8
#define CC     256
#define C4     (CC / 4)                 // 64 f32x4 per row
#define ROWS   (BB * ANCHOR * ANCHOR)   // 392 rows per box

typedef float f32x4 __attribute__((ext_vector_type(4)));

__global__ __launch_bounds__(256) void roi_crop_kernel(
    const f32x4* __restrict__ fin,      // features as f32x4
    const int*   __restrict__ boxes,    // [N,4]
    f32x4*       __restrict__ fout)     // out as f32x4
{
    const int lane = threadIdx.x & 63;
    const int wave = threadIdx.x >> 6;          // 0..3
    const int x    = blockIdx.x;                // 0..1999
    const int b    = x & 7;                     // batch slice == XCD id
    const int n    = (x >> 3) * 4 + wave;       // box index, 0..999

    int x1 = boxes[n * 4 + 0];
    int y1 = boxes[n * 4 + 1];
    x1 = min(max(x1, 0), FS - ANCHOR);
    y1 = min(max(y1, 0), FS - ANCHOR);

    const f32x4* __restrict__ src = fin + ((b * FS + x1) * FS + y1) * C4 + lane;
    f32x4* __restrict__ dst = fout + n * (ROWS * C4) + b * (ANCHOR * ANCHOR * C4) + lane;

    f32x4 buf[2][ANCHOR];

    // prologue: load row 0
    #pragma unroll
    for (int j = 0; j < ANCHOR; ++j)
        buf[0][j] = src[j * C4];

    #pragma unroll
    for (int i = 0; i < ANCHOR; ++i) {
        if (i + 1 < ANCHOR) {               // load row i+1 first (next buffer)
            #pragma unroll
            for (int j = 0; j < ANCHOR; ++j)
                buf[(i + 1) & 1][j] = src[((i + 1) * FS + j) * C4];
        }
        #pragma unroll
        for (int j = 0; j < ANCHOR; ++j)    // then store row i (current buffer)
            __builtin_nontemporal_store(buf[i & 1][j], &dst[(i * ANCHOR + j) * C4]);
    }
}

extern "C" void kernel_launch(void* const* d_in, const int* in_sizes, int n_in,
                              void* d_out, int out_size, void* d_ws, size_t ws_size,
                              hipStream_t stream) {
    const f32x4* fin  = (const f32x4*)d_in[0];
    const int*  boxes = (const int*)d_in[1];
    f32x4*      fout  = (f32x4*)d_out;

    roi_crop_kernel<<<NBOX * BB / 4, 256, 0, stream>>>(fin, boxes, fout);
}